// Round 2
// baseline (618.250 us; speedup 1.0000x reference)
//
#include <hip/hip_runtime.h>
#include <math.h>

#define RES   1024
#define FEATC 12
#define CBN   32
#define H_IMG 1080
#define W_IMG 1920
#define NPIX  (H_IMG * W_IMG)

__global__ __launch_bounds__(256) void sky_kernel(
    const float* __restrict__ rays_d,   // [NPIX,3]
    const int*   __restrict__ mask,     // [NPIX]
    const float* __restrict__ cube,     // [6,RES,RES,12]
    const float* __restrict__ cb,       // [32,12]
    const float* __restrict__ W1,       // [15,32]
    const float* __restrict__ b1,       // [32]
    const float* __restrict__ W2,       // [32,32]
    const float* __restrict__ b2,       // [32]
    const float* __restrict__ W3,       // [32,3]
    const float* __restrict__ b3,       // [3]
    float*       __restrict__ out)      // [3,NPIX]
{
    __shared__ float sW1[15 * 32];
    __shared__ float sb1[32];
    __shared__ float sW2[32 * 32];
    __shared__ float sb2[32];
    __shared__ float sW3[32 * 3];
    __shared__ float sb3[3];
    __shared__ float sCB[CBN * FEATC];

    for (int t = threadIdx.x; t < 15 * 32; t += blockDim.x) sW1[t] = W1[t];
    for (int t = threadIdx.x; t < 32;      t += blockDim.x) sb1[t] = b1[t];
    for (int t = threadIdx.x; t < 32 * 32; t += blockDim.x) sW2[t] = W2[t];
    for (int t = threadIdx.x; t < 32;      t += blockDim.x) sb2[t] = b2[t];
    for (int t = threadIdx.x; t < 32 * 3;  t += blockDim.x) sW3[t] = W3[t];
    for (int t = threadIdx.x; t < 3;       t += blockDim.x) sb3[t] = b3[t];
    for (int t = threadIdx.x; t < CBN * FEATC; t += blockDim.x) sCB[t] = cb[t];
    __syncthreads();

    const int i = blockIdx.x * blockDim.x + threadIdx.x;
    if (i >= NPIX) return;

    if (mask[i] == 0) {
        out[0 * NPIX + i] = 0.0f;
        out[1 * NPIX + i] = 0.0f;
        out[2 * NPIX + i] = 0.0f;
        return;
    }

    const float x = rays_d[3 * i + 0];
    const float y = rays_d[3 * i + 1];
    const float z = rays_d[3 * i + 2];

    const float ax = fabsf(x), ay = fabsf(y), az = fabsf(z);
    const bool is_x = (ax >= ay) && (ax >= az);
    const bool is_y = (!is_x) && (ay >= az);

    int face; float ma, u, v;
    if (is_x) {
        face = (x >= 0.0f) ? 0 : 1;
        ma = ax;
        u = (x >= 0.0f) ? -z : z;
        v = -y;
    } else if (is_y) {
        face = (y >= 0.0f) ? 2 : 3;
        ma = ay;
        u = x;
        v = (y >= 0.0f) ? z : -z;
    } else {
        face = (z >= 0.0f) ? 4 : 5;
        ma = az;
        u = (z >= 0.0f) ? x : -x;
        v = -y;
    }

    // s = (u / (ma + eps) + 1.0) * 0.5 * R - 0.5, each op individually rounded
    const float denom = __fadd_rn(ma, 1e-9f);
    const float s = __fsub_rn(__fmul_rn(__fmul_rn(__fadd_rn(__fdiv_rn(u, denom), 1.0f), 0.5f), (float)RES), 0.5f);
    const float t = __fsub_rn(__fmul_rn(__fmul_rn(__fadd_rn(__fdiv_rn(v, denom), 1.0f), 0.5f), (float)RES), 0.5f);

    const float x0f = floorf(s);
    const float y0f = floorf(t);
    const float fx = __fsub_rn(s, x0f);
    const float fy = __fsub_rn(t, y0f);

    int x0i = (int)x0f; x0i = min(max(x0i, 0), RES - 1);
    int x1i = min(x0i + 1, RES - 1);
    int y0i = (int)y0f; y0i = min(max(y0i, 0), RES - 1);
    int y1i = min(y0i + 1, RES - 1);

    const size_t fbase = (size_t)face * RES * RES;
    const size_t off00 = (fbase + (size_t)y0i * RES + x0i) * FEATC;
    const size_t off01 = (fbase + (size_t)y0i * RES + x1i) * FEATC;
    const size_t off10 = (fbase + (size_t)y1i * RES + x0i) * FEATC;
    const size_t off11 = (fbase + (size_t)y1i * RES + x1i) * FEATC;

    const float4* p00 = (const float4*)(cube + off00);
    const float4* p01 = (const float4*)(cube + off01);
    const float4* p10 = (const float4*)(cube + off10);
    const float4* p11 = (const float4*)(cube + off11);

    float c00[FEATC], c01[FEATC], c10[FEATC], c11[FEATC];
    #pragma unroll
    for (int q4 = 0; q4 < 3; ++q4) {
        float4 a = p00[q4]; c00[4*q4+0]=a.x; c00[4*q4+1]=a.y; c00[4*q4+2]=a.z; c00[4*q4+3]=a.w;
        float4 b = p01[q4]; c01[4*q4+0]=b.x; c01[4*q4+1]=b.y; c01[4*q4+2]=b.z; c01[4*q4+3]=b.w;
        float4 c = p10[q4]; c10[4*q4+0]=c.x; c10[4*q4+1]=c.y; c10[4*q4+2]=c.z; c10[4*q4+3]=c.w;
        float4 dd= p11[q4]; c11[4*q4+0]=dd.x;c11[4*q4+1]=dd.y;c11[4*q4+2]=dd.z;c11[4*q4+3]=dd.w;
    }

    // bilinear: exactly the reference's op order, each op individually rounded
    const float omfx = __fsub_rn(1.0f, fx);
    const float omfy = __fsub_rn(1.0f, fy);
    float feat[FEATC];
    #pragma unroll
    for (int k = 0; k < FEATC; ++k) {
        const float top = __fadd_rn(__fmul_rn(c00[k], omfx), __fmul_rn(c01[k], fx));
        const float bot = __fadd_rn(__fmul_rn(c10[k], omfx), __fmul_rn(c11[k], fx));
        feat[k] = __fadd_rn(__fmul_rn(top, omfy), __fmul_rn(bot, fy));
    }

    // argmin in fp64: exact decision given the (bit-matched) fp32 feat
    int best = 0;
    double bestd = 1e300;
    for (int j = 0; j < CBN; ++j) {
        double d2 = 0.0;
        #pragma unroll
        for (int k = 0; k < FEATC; ++k) {
            const double diff = (double)feat[k] - (double)sCB[j * FEATC + k];
            d2 += diff * diff;
        }
        if (d2 < bestd) { bestd = d2; best = j; }
    }

    // straight-through: q = feat + (cb[best] - feat), elementwise rounding
    float hin[15];
    #pragma unroll
    for (int k = 0; k < FEATC; ++k)
        hin[k] = __fadd_rn(feat[k], __fsub_rn(sCB[best * FEATC + k], feat[k]));
    hin[12] = x; hin[13] = y; hin[14] = z;

    float h1[32];
    #pragma unroll
    for (int k = 0; k < 32; ++k) {
        float a = sb1[k];
        #pragma unroll
        for (int j = 0; j < 15; ++j) a += hin[j] * sW1[j * 32 + k];
        h1[k] = fmaxf(a, 0.0f);
    }

    float h2[32];
    #pragma unroll
    for (int k = 0; k < 32; ++k) {
        float a = sb2[k];
        #pragma unroll
        for (int j = 0; j < 32; ++j) a += h1[j] * sW2[j * 32 + k];
        h2[k] = fmaxf(a, 0.0f);
    }

    #pragma unroll
    for (int c = 0; c < 3; ++c) {
        float a = sb3[c];
        #pragma unroll
        for (int j = 0; j < 32; ++j) a += h2[j] * sW3[j * 3 + c];
        float r = 1.0f / (1.0f + expf(-a));
        r = fminf(fmaxf(r, 0.0f), 1.0f);
        out[(size_t)c * NPIX + i] = r;
    }
}

extern "C" void kernel_launch(void* const* d_in, const int* in_sizes, int n_in,
                              void* d_out, int out_size, void* d_ws, size_t ws_size,
                              hipStream_t stream) {
    const float* rays_d = (const float*)d_in[0];
    const int*   mask   = (const int*)d_in[1];
    const float* cube   = (const float*)d_in[2];
    const float* cb     = (const float*)d_in[3];
    const float* W1     = (const float*)d_in[4];
    const float* b1     = (const float*)d_in[5];
    const float* W2     = (const float*)d_in[6];
    const float* b2     = (const float*)d_in[7];
    const float* W3     = (const float*)d_in[8];
    const float* b3     = (const float*)d_in[9];
    float* out = (float*)d_out;

    const int block = 256;
    const int grid = (NPIX + block - 1) / block;  // 8100 exactly
    sky_kernel<<<grid, block, 0, stream>>>(rays_d, mask, cube, cb,
                                           W1, b1, W2, b2, W3, b3, out);
}